// Round 9
// baseline (128.202 us; speedup 1.0000x reference)
//
#include <hip/hip_runtime.h>
#include <hip/hip_cooperative_groups.h>

namespace cg = cooperative_groups;

// x: (2, 16, 512, 12) f32 ; cuts: (12,1) f32 ; leaf_score: (4096,1000) f32
// out: (16,1000) f32
// leaf[b,t,l] = prod_i h[i][bit_i(l)], h[i][0]=x, h[i][1]=2x-cut_i
// out[b,c] = sum_l (1/T * sum_t leaf[b,t,l]) * score[l,c]
#define HF 12
#define NLEAF 4096
#define NB 16
#define NT 512
#define NC 1000
#define NTC 8                 // t-chunks per b
#define TCH 64                // t per k1 block
#define TSUB 16               // t per phase
#define NSUB (TCH / TSUB)     // 4 phases
#define LCH 64                // l per gemm block
#define NLCH (NLEAF / LCH)    // 64
#define NCT 4                 // c-tiles of 256
#define INVT (1.0f / 512.0f)
#define NBLK 256              // = NLCH*NCT = CU count -> co-resident

// ---------------------------------------------------------------------------
// Single cooperative kernel, grid = 256 blocks x 256 threads (1 block/CU).
// Phase 1: blocks 0..127 compute Sp[blk][l] (64-t partial leaf sums);
//          blocks 128..255 zero out[16][1000].
// grid.sync()
// Phase 2: all blocks: (lc,ct) = (blk/4, blk%4); reduce Sp -> LDS Stl,
//          acc[b] = sum_l Stl[b][l]*score[l][c], atomicAdd into out.
// ---------------------------------------------------------------------------
__global__ __launch_bounds__(256) void ndt_fused(
    const float* __restrict__ x, const float* __restrict__ cuts,
    const float* __restrict__ score, float* __restrict__ Sp,
    float* __restrict__ out) {
  const int blk = blockIdx.x;
  const int tid = threadIdx.x;

  __shared__ float h0s[TSUB][HF], h1s[TSUB][HF];
  __shared__ float Phis[TSUB][64], Plos[TSUB][64];
  __shared__ float Stl[NB][LCH];

  if (blk < NB * NTC) {
    // ---- phase 1a: k1 body (64 t per block) ----
    const float* xb = x + (size_t)NB * NT * HF + (size_t)blk * (TCH * HF);

    const int  tl  = tid / HF;
    const int  f   = tid - tl * HF;
    const bool ldr = (tid < TSUB * HF);   // 192 loader threads
    const float cf = ldr ? cuts[f] : 0.f;
    float xv = ldr ? xb[tid] : 0.f;       // prefetched phase-0 x

    float acc[16];
#pragma unroll
    for (int k = 0; k < 16; ++k) acc[k] = 0.f;

    const int w  = tid >> 6;   // wave id 0..3
    const int lo = tid & 63;

    for (int ts = 0; ts < NSUB; ++ts) {
      if (ldr) {
        h0s[tl][f] = xv;
        h1s[tl][f] = 2.f * xv - cf;
      }
      __syncthreads();
      if (ldr && ts + 1 < NSUB) xv = xb[(ts + 1) * TSUB * HF + tid];  // prefetch

      // P-compute: 2048 tasks = 16 t * (hi|lo) * 64, 8 per thread.
#pragma unroll
      for (int r = 0; r < 8; ++r) {
        const int task = r * 256 + tid;
        const int t2   = task >> 7;
        const int half = (task >> 6) & 1;
        const int idx  = task & 63;
        const float* hh0 = h0s[t2];
        const float* hh1 = h1s[t2];
        float p = 1.f;
#pragma unroll
        for (int i = 0; i < 6; ++i) {
          const int ff  = half * 6 + i;
          const int bit = (idx >> (5 - i)) & 1;
          p *= bit ? hh1[ff] : hh0[ff];
        }
        if (half) Plos[t2][idx] = p;
        else      Phis[t2][(idx & 3) * 16 + (idx >> 2)] = p;  // permuted for b128
      }
      __syncthreads();

#pragma unroll
      for (int t2 = 0; t2 < TSUB; ++t2) {
        const float  plo = Plos[t2][lo];
        const float4* ph = (const float4*)&Phis[t2][w * 16];  // broadcast reads
        const float4 p0 = ph[0], p1 = ph[1], p2 = ph[2], p3 = ph[3];
        acc[0]  += p0.x * plo;  acc[1]  += p0.y * plo;
        acc[2]  += p0.z * plo;  acc[3]  += p0.w * plo;
        acc[4]  += p1.x * plo;  acc[5]  += p1.y * plo;
        acc[6]  += p1.z * plo;  acc[7]  += p1.w * plo;
        acc[8]  += p2.x * plo;  acc[9]  += p2.y * plo;
        acc[10] += p2.z * plo;  acc[11] += p2.w * plo;
        acc[12] += p3.x * plo;  acc[13] += p3.y * plo;
        acc[14] += p3.z * plo;  acc[15] += p3.w * plo;
      }
    }

    float* sp = Sp + (size_t)blk * NLEAF;
#pragma unroll
    for (int k = 0; k < 16; ++k) sp[k * 256 + tid] = acc[k];
  } else {
    // ---- phase 1b: zero out[16][1000] (32768 threads cover 16000) ----
    const int i = (blk - NB * NTC) * 256 + tid;
    if (i < NB * NC) out[i] = 0.f;
  }

  cg::this_grid().sync();

  // ---- phase 2: k2f body ----
  const int lc = blk / NCT;
  const int ct = blk % NCT;

  for (int i = tid; i < NB * LCH; i += 256) {
    const int b  = i >> 6;
    const int ll = i & 63;
    const float* sp = Sp + (size_t)(b * NTC) * NLEAF + lc * LCH + ll;
    float v = 0.f;
#pragma unroll
    for (int tc = 0; tc < NTC; ++tc) v += sp[(size_t)tc * NLEAF];
    Stl[b][ll] = v * INVT;
  }
  __syncthreads();

  const int c = ct * 256 + tid;
  if (c < NC) {
    float acc2[NB];
#pragma unroll
    for (int b = 0; b < NB; ++b) acc2[b] = 0.f;

    const float* sc = score + (size_t)(lc * LCH) * NC + c;
    for (int l0 = 0; l0 < LCH; l0 += 8) {
      float sv[8];
#pragma unroll
      for (int j = 0; j < 8; ++j) sv[j] = sc[(size_t)(l0 + j) * NC];
#pragma unroll
      for (int b = 0; b < NB; ++b) {
        const float4* r = (const float4*)&Stl[b][l0];  // 32B-aligned broadcast
        const float4 r0 = r[0], r1 = r[1];
        acc2[b] += r0.x * sv[0] + r0.y * sv[1] + r0.z * sv[2] + r0.w * sv[3]
                 + r1.x * sv[4] + r1.y * sv[5] + r1.z * sv[6] + r1.w * sv[7];
      }
    }
#pragma unroll
    for (int b = 0; b < NB; ++b)
      atomicAdd(&out[b * NC + c], acc2[b]);  // coalesced addresses per wave
  }
}

extern "C" void kernel_launch(void* const* d_in, const int* in_sizes, int n_in,
                              void* d_out, int out_size, void* d_ws, size_t ws_size,
                              hipStream_t stream) {
  const float* x     = (const float*)d_in[0];
  const float* cuts  = (const float*)d_in[1];
  const float* score = (const float*)d_in[2];
  float* out = (float*)d_out;
  float* Sp  = (float*)d_ws;   // [128][4096]  2 MB

  void* args[] = {(void*)&x, (void*)&cuts, (void*)&score, (void*)&Sp, (void*)&out};
  hipLaunchCooperativeKernel((const void*)ndt_fused, dim3(NBLK), dim3(256),
                             args, 0, stream);
}

// Round 12
// 84.648 us; speedup vs baseline: 1.5145x; 1.5145x over previous
//
#include <hip/hip_runtime.h>

// x: (2, 16, 512, 12) f32 ; cuts: (12,1) f32 ; leaf_score: (4096,1000) f32
// out: (16,1000) f32
// leaf[b,t,l] = prod_i h[i][bit_i(l)], h[i][0]=x, h[i][1]=2x-cut_i
// out[b,c] = sum_l (1/T * sum_t leaf[b,t,l]) * score[l,c]
#define HF 12
#define NLEAF 4096
#define NB 16
#define NT 512
#define NC 1000
#define NTC 8                 // t-chunks per b
#define TCH 64                // t per block
#define TSUB 16               // t per phase
#define NSUB (TCH / TSUB)     // 4 phases
#define LCH 64                // l per k2 block
#define NLCH (NLEAF / LCH)    // 64
#define NCT 4                 // c-tiles of 256
#define INVT (1.0f / 512.0f)

// ---------------------------------------------------------------------------
// k1: partial S + out-zeroing. grid = NB*NTC = 128 blocks, 256 threads.
// Sp[blk][l] = sum over this block's 64 t of leaf[b,t,l]. Plain stores.
// Also zeroes out[16][1000] (32768 threads >= 16000); the kernel boundary
// before k2f makes the zeroing device-visible to k2f's atomics.
// NOTE (r9): cg::this_grid().sync() measured ~40us @256 blocks on gfx950 —
// kernel boundaries (~2us) are the cheap cross-block barrier. Don't fuse.
// ---------------------------------------------------------------------------
__global__ __launch_bounds__(256) void k1_leaf(const float* __restrict__ x,
                                               const float* __restrict__ cuts,
                                               float* __restrict__ Sp,
                                               float* __restrict__ out) {
  const int blk = blockIdx.x;
  const int tid = threadIdx.x;

  // fold the out-memset into this dispatch (saves a ~2us dispatch slot)
  {
    const int i = blk * 256 + tid;
    if (i < NB * NC) out[i] = 0.f;
  }

  __shared__ float h0s[TSUB][HF], h1s[TSUB][HF];
  __shared__ float Phis[TSUB][64], Plos[TSUB][64];

  const float* xb = x + (size_t)NB * NT * HF + (size_t)blk * (TCH * HF);

  const int  tl  = tid / HF;
  const int  f   = tid - tl * HF;
  const bool ldr = (tid < TSUB * HF);   // 192 loader threads
  const float cf = ldr ? cuts[f] : 0.f;
  float xv = ldr ? xb[tid] : 0.f;       // prefetched phase-0 x

  float acc[16];
#pragma unroll
  for (int k = 0; k < 16; ++k) acc[k] = 0.f;

  const int w  = tid >> 6;   // wave id 0..3
  const int lo = tid & 63;

  for (int ts = 0; ts < NSUB; ++ts) {
    if (ldr) {
      h0s[tl][f] = xv;
      h1s[tl][f] = 2.f * xv - cf;
    }
    __syncthreads();
    if (ldr && ts + 1 < NSUB) xv = xb[(ts + 1) * TSUB * HF + tid];  // prefetch

    // P-compute: 2048 tasks = 16 t * (hi|lo) * 64, 8 per thread.
#pragma unroll
    for (int r = 0; r < 8; ++r) {
      const int task = r * 256 + tid;
      const int t2   = task >> 7;
      const int half = (task >> 6) & 1;
      const int idx  = task & 63;
      const float* hh0 = h0s[t2];
      const float* hh1 = h1s[t2];
      float p = 1.f;
#pragma unroll
      for (int i = 0; i < 6; ++i) {
        const int ff  = half * 6 + i;
        const int bit = (idx >> (5 - i)) & 1;
        p *= bit ? hh1[ff] : hh0[ff];
      }
      if (half) Plos[t2][idx] = p;
      else      Phis[t2][(idx & 3) * 16 + (idx >> 2)] = p;  // permuted for b128 read
    }
    __syncthreads();

#pragma unroll
    for (int t2 = 0; t2 < TSUB; ++t2) {
      const float  plo = Plos[t2][lo];
      const float4* ph = (const float4*)&Phis[t2][w * 16];  // broadcast reads
      const float4 p0 = ph[0], p1 = ph[1], p2 = ph[2], p3 = ph[3];
      acc[0]  += p0.x * plo;  acc[1]  += p0.y * plo;
      acc[2]  += p0.z * plo;  acc[3]  += p0.w * plo;
      acc[4]  += p1.x * plo;  acc[5]  += p1.y * plo;
      acc[6]  += p1.z * plo;  acc[7]  += p1.w * plo;
      acc[8]  += p2.x * plo;  acc[9]  += p2.y * plo;
      acc[10] += p2.z * plo;  acc[11] += p2.w * plo;
      acc[12] += p3.x * plo;  acc[13] += p3.y * plo;
      acc[14] += p3.z * plo;  acc[15] += p3.w * plo;
    }
  }

  float* sp = Sp + (size_t)blk * NLEAF;
#pragma unroll
  for (int k = 0; k < 16; ++k) sp[k * 256 + tid] = acc[k];
}

// ---------------------------------------------------------------------------
// k2f: fused (k15 + gemm + out-reduce). grid = NLCH*NCT = 256 blocks.
// Block (lc,ct): reduce Sp partials for its 64-l chunk into LDS Stl[b][ll],
// then acc[b] = sum_l Stl[b][l] * score[l][c], atomicAdd into out[b][c].
// ---------------------------------------------------------------------------
__global__ __launch_bounds__(256) void k2f(const float* __restrict__ Sp,
                                           const float* __restrict__ score,
                                           float* __restrict__ out) {
  const int lc  = blockIdx.x / NCT;   // ct-blocks with same lc adjacent (L2 reuse)
  const int ct  = blockIdx.x % NCT;
  const int tid = threadIdx.x;

  __shared__ float Stl[NB][LCH];      // 4 KB

  for (int i = tid; i < NB * LCH; i += 256) {
    const int b  = i >> 6;
    const int ll = i & 63;
    const float* sp = Sp + (size_t)(b * NTC) * NLEAF + lc * LCH + ll;
    float v = 0.f;
#pragma unroll
    for (int tc = 0; tc < NTC; ++tc) v += sp[(size_t)tc * NLEAF];
    Stl[b][ll] = v * INVT;
  }
  __syncthreads();

  const int c = ct * 256 + tid;
  if (c < NC) {
    float acc[NB];
#pragma unroll
    for (int b = 0; b < NB; ++b) acc[b] = 0.f;

    const float* sc = score + (size_t)(lc * LCH) * NC + c;
    for (int l0 = 0; l0 < LCH; l0 += 8) {
      float sv[8];
#pragma unroll
      for (int j = 0; j < 8; ++j) sv[j] = sc[(size_t)(l0 + j) * NC];
#pragma unroll
      for (int b = 0; b < NB; ++b) {
        const float4* r = (const float4*)&Stl[b][l0];  // 32B-aligned broadcast
        const float4 r0 = r[0], r1 = r[1];
        acc[b] += r0.x * sv[0] + r0.y * sv[1] + r0.z * sv[2] + r0.w * sv[3]
                + r1.x * sv[4] + r1.y * sv[5] + r1.z * sv[6] + r1.w * sv[7];
      }
    }
#pragma unroll
    for (int b = 0; b < NB; ++b)
      atomicAdd(&out[b * NC + c], acc[b]);  // coalesced addresses per wave
  }
}

extern "C" void kernel_launch(void* const* d_in, const int* in_sizes, int n_in,
                              void* d_out, int out_size, void* d_ws, size_t ws_size,
                              hipStream_t stream) {
  const float* x     = (const float*)d_in[0];
  const float* cuts  = (const float*)d_in[1];
  const float* score = (const float*)d_in[2];
  float* out = (float*)d_out;

  float* Sp = (float*)d_ws;   // [128][4096]  2 MB

  k1_leaf<<<NB * NTC, 256, 0, stream>>>(x, cuts, Sp, out);
  k2f<<<NLCH * NCT, 256, 0, stream>>>(Sp, score, out);
}